// Round 1
// baseline (475.958 us; speedup 1.0000x reference)
//
#include <hip/hip_runtime.h>

// Problem constants
#define NPTS 131072       // 32*64*64 spatial points
#define KCODES 512
#define DIM 64
#define HW 4096           // 64*64
#define BATCH_STRIDE 262144  // 64*64*64 (C*H*W)
#define NELEM 8388608     // 32*64*64*64

// Output layout (floats): [0]=loss, [1..8388608]=quantized BCHW,
// [8388609]=perplexity, [8388610..]=encodings (N x K)
#define QUANT_OFF 1
#define PERP_OFF 8388609
#define ENC_OFF  8388610

// ws layout:
// [0, 2048)            counts (512 x u32)
// [2048, 2052)         float loss accumulator
// [4096, 8192)         sw2 (512 x double)
// [8192, 8192+262144)  idx (u16 x 131072)

__global__ void vq_prep(const float* __restrict__ W, double* __restrict__ sw2) {
  int k = blockIdx.x;     // 512 blocks
  int d = threadIdx.x;    // 64 threads
  double wd = (double)W[k * 64 + d];
  double s = wd * wd;
  #pragma unroll
  for (int off = 32; off; off >>= 1) s += __shfl_down(s, off);
  if (d == 0) sw2[k] = s;
}

__global__ __launch_bounds__(256, 2) void vq_argmin(
    const float* __restrict__ x, const float* __restrict__ W,
    const double* __restrict__ sw2, unsigned short* __restrict__ idx_out,
    float* __restrict__ enc, unsigned int* __restrict__ counts,
    float* __restrict__ accum) {
  __shared__ double wlds[128 * 64];   // 64 KB: 128 codebook rows as f64
  __shared__ unsigned int hcnt[512];
  __shared__ float lred[4];

  int tid = threadIdx.x;
  hcnt[tid] = 0u;
  hcnt[tid + 256] = 0u;

  int n  = blockIdx.x * 256 + tid;    // point id
  int b  = n >> 12;                   // batch
  int hw = n & 4095;
  const float* xp = x + b * BATCH_STRIDE + hw;  // channel stride 4096

  // Load this point's 64 channels as f64 (coalesced across lanes per channel)
  double xv[64];
  double cn = 0.0;
  #pragma unroll
  for (int c = 0; c < 64; ++c) {
    double v = (double)xp[c * 4096];
    xv[c] = v;
    cn = fma(v, v, cn);
  }

  double best = 1e300;
  int bi = 0;

  for (int k0 = 0; k0 < 512; k0 += 128) {
    __syncthreads();
    // stage 128 rows (8192 doubles) — 32 per thread, coalesced from global
    #pragma unroll
    for (int j = 0; j < 32; ++j) {
      int t = tid + j * 256;
      wlds[t] = (double)W[k0 * 64 + t];
    }
    __syncthreads();

    for (int kk = 0; kk < 128; ++kk) {
      const double* wr = &wlds[kk << 6];
      double a0 = 0.0, a1 = 0.0, a2 = 0.0, a3 = 0.0;
      #pragma unroll
      for (int d2 = 0; d2 < 64; d2 += 4) {
        a0 = fma(xv[d2 + 0], wr[d2 + 0], a0);
        a1 = fma(xv[d2 + 1], wr[d2 + 1], a1);
        a2 = fma(xv[d2 + 2], wr[d2 + 2], a2);
        a3 = fma(xv[d2 + 3], wr[d2 + 3], a3);
      }
      double score = sw2[k0 + kk] - 2.0 * ((a0 + a1) + (a2 + a3));
      if (score < best) { best = score; bi = k0 + kk; }
    }
  }

  idx_out[n] = (unsigned short)bi;
  enc[(long long)n * 512 + bi] = 1.0f;   // region was memset to 0 beforehand
  atomicAdd(&hcnt[bi], 1u);

  // loss partial: squared distance = ||x||^2 + (sw2 - 2 dot) = cn + best
  float dl = (float)(cn + best);
  #pragma unroll
  for (int off = 32; off; off >>= 1) dl += __shfl_down(dl, off);
  if ((tid & 63) == 0) lred[tid >> 6] = dl;
  __syncthreads();
  if (tid == 0) atomicAdd(accum, lred[0] + lred[1] + lred[2] + lred[3]);

  // flush histogram
  unsigned int v0 = hcnt[tid], v1 = hcnt[tid + 256];
  if (v0) atomicAdd(&counts[tid], v0);
  if (v1) atomicAdd(&counts[tid + 256], v1);
}

__global__ void vq_quant(const float* __restrict__ W,
                         const unsigned short* __restrict__ idx,
                         float* __restrict__ quant) {
  int e  = blockIdx.x * 256 + threadIdx.x;  // output element (BCHW order)
  int b  = e >> 18;          // / 262144
  int r  = e & 262143;
  int c  = r >> 12;          // channel
  int hw = r & 4095;
  int n  = (b << 12) | hw;
  quant[e] = W[((int)idx[n] << 6) | c];
}

__global__ void vq_final(const unsigned int* __restrict__ counts,
                         const float* __restrict__ accum,
                         float* __restrict__ out) {
  __shared__ float red[8];
  int k = threadIdx.x;  // 512 threads
  float p = (float)counts[k] * (1.0f / 131072.0f);
  float t = p * logf(p + 1e-10f);
  float s = t;
  #pragma unroll
  for (int off = 32; off; off >>= 1) s += __shfl_down(s, off);
  if ((k & 63) == 0) red[k >> 6] = s;
  __syncthreads();
  if (k == 0) {
    float H = 0.0f;
    #pragma unroll
    for (int i = 0; i < 8; ++i) H += red[i];
    out[PERP_OFF] = expf(-H);
    out[0] = 1.25f * accum[0] * (1.0f / 8388608.0f);
  }
}

extern "C" void kernel_launch(void* const* d_in, const int* in_sizes, int n_in,
                              void* d_out, int out_size, void* d_ws, size_t ws_size,
                              hipStream_t stream) {
  const float* x = (const float*)d_in[0];
  const float* W = (const float*)d_in[1];
  float* out   = (float*)d_out;
  float* quant = out + QUANT_OFF;
  float* enc   = out + ENC_OFF;

  char* ws = (char*)d_ws;
  unsigned int* counts = (unsigned int*)ws;
  float* accum         = (float*)(ws + 2048);
  double* sw2          = (double*)(ws + 4096);
  unsigned short* idx  = (unsigned short*)(ws + 8192);

  hipMemsetAsync(ws, 0, 4096, stream);
  hipMemsetAsync(enc, 0, (size_t)67108864 * 4, stream);

  vq_prep<<<512, 64, 0, stream>>>(W, sw2);
  vq_argmin<<<512, 256, 0, stream>>>(x, W, sw2, idx, enc, counts, accum);
  vq_quant<<<32768, 256, 0, stream>>>(W, idx, quant);
  vq_final<<<1, 512, 0, stream>>>(counts, accum, out);
}

// Round 2
// 321.310 us; speedup vs baseline: 1.4813x; 1.4813x over previous
//
#include <hip/hip_runtime.h>

// Output layout (floats): [0]=loss, [1..8388608]=quantized BCHW,
// [8388609]=perplexity, [8388610..]=encodings (N x K)
#define QUANT_OFF 1
#define PERP_OFF 8388609
#define ENC_OFF  8388610

// ws layout: [0,2048) counts u32[512]; [2048,2052) float loss accum;
//            [4096,6144) sw2 float[512]

__global__ void vq_prep(const float* __restrict__ W, float* __restrict__ sw2) {
  int k = blockIdx.x;     // 512 blocks
  int d = threadIdx.x;    // 64 threads
  float wd = W[k * 64 + d];
  float s = wd * wd;
  #pragma unroll
  for (int off = 32; off; off >>= 1) s += __shfl_down(s, off, 64);
  if (d == 0) sw2[k] = s;
}

__global__ __launch_bounds__(256) void vq_main(
    const float* __restrict__ x, const float* __restrict__ W,
    const float* __restrict__ sw2, float* __restrict__ enc,
    float* __restrict__ quant, unsigned int* __restrict__ counts,
    float* __restrict__ accum) {
  __shared__ unsigned int hcnt[512];
  __shared__ float lred[4];

  int tid  = threadIdx.x;
  int lane = tid & 63;
  int n  = blockIdx.x * 256 + tid;    // point id
  int b  = n >> 12;
  int hw = n & 4095;
  const float* xp = x + b * 262144 + hw;   // channel stride 4096 floats

  hcnt[tid] = 0u;
  hcnt[tid + 256] = 0u;

  // Load the point's 64 channels (coalesced across lanes per channel)
  float xv[64];
  float cn = 0.0f;
  #pragma unroll
  for (int c = 0; c < 64; ++c) {
    float v = xp[c * 4096];
    xv[c] = v;
    cn = fmaf(v, v, cn);
  }

  float best = 3.4e38f;
  int bi = 0;

  // 512 codes, unrolled by 2; W/sw2 addresses are wave-uniform -> s_loads
  for (int k = 0; k < 512; k += 2) {
    const float* w0 = W + (k << 6);
    const float* w1 = w0 + 64;
    float a0 = 0.f, a1 = 0.f, a2 = 0.f, a3 = 0.f;
    float c0 = 0.f, c1 = 0.f, c2 = 0.f, c3 = 0.f;
    #pragma unroll
    for (int d = 0; d < 64; d += 4) {
      a0 = fmaf(xv[d + 0], w0[d + 0], a0);
      a1 = fmaf(xv[d + 1], w0[d + 1], a1);
      a2 = fmaf(xv[d + 2], w0[d + 2], a2);
      a3 = fmaf(xv[d + 3], w0[d + 3], a3);
      c0 = fmaf(xv[d + 0], w1[d + 0], c0);
      c1 = fmaf(xv[d + 1], w1[d + 1], c1);
      c2 = fmaf(xv[d + 2], w1[d + 2], c2);
      c3 = fmaf(xv[d + 3], w1[d + 3], c3);
    }
    float s0 = sw2[k]     - 2.0f * ((a0 + a1) + (a2 + a3));
    float s1 = sw2[k + 1] - 2.0f * ((c0 + c1) + (c2 + c3));
    if (s0 < best) { best = s0; bi = k; }
    if (s1 < best) { best = s1; bi = k + 1; }
  }

  // ---- quantized output (BCHW): coalesced strided stores ----
  {
    const float4* wrow = (const float4*)(W + (bi << 6));
    float* qp = quant + b * 262144 + hw;
    #pragma unroll
    for (int q4 = 0; q4 < 16; ++q4) {
      float4 wv = wrow[q4];
      qp[(q4 * 4 + 0) * 4096] = wv.x;
      qp[(q4 * 4 + 1) * 4096] = wv.y;
      qp[(q4 * 4 + 2) * 4096] = wv.z;
      qp[(q4 * 4 + 3) * 4096] = wv.w;
    }
  }

  // ---- one-hot rows, wave-cooperative (row r = lane r's point) ----
  {
    float* ebase = enc + (long long)(blockIdx.x * 256 + (tid & ~63)) * 512;
    for (int r = 0; r < 64; ++r) {
      int rb = __shfl(bi, r, 64);
      float* rowp = ebase + r * 512 + lane * 8;   // 8B aligned
      int bj = lane * 8;
      #pragma unroll
      for (int p = 0; p < 4; ++p) {
        float2 v;
        v.x = (bj + 2 * p     == rb) ? 1.0f : 0.0f;
        v.y = (bj + 2 * p + 1 == rb) ? 1.0f : 0.0f;
        ((float2*)rowp)[p] = v;
      }
    }
  }

  // ---- histogram + loss ----
  __syncthreads();
  atomicAdd(&hcnt[bi], 1u);

  float dl = cn + best;   // ||x||^2 + (||w||^2 - 2 x.w) = min squared dist
  #pragma unroll
  for (int off = 32; off; off >>= 1) dl += __shfl_down(dl, off, 64);
  if (lane == 0) lred[tid >> 6] = dl;
  __syncthreads();
  if (tid == 0) atomicAdd(accum, (lred[0] + lred[1]) + (lred[2] + lred[3]));

  unsigned int v0 = hcnt[tid], v1 = hcnt[tid + 256];
  if (v0) atomicAdd(&counts[tid], v0);
  if (v1) atomicAdd(&counts[tid + 256], v1);
}

__global__ void vq_final(const unsigned int* __restrict__ counts,
                         const float* __restrict__ accum,
                         float* __restrict__ out) {
  __shared__ float red[8];
  int k = threadIdx.x;  // 512 threads
  float p = (float)counts[k] * (1.0f / 131072.0f);
  float s = p * logf(p + 1e-10f);
  #pragma unroll
  for (int off = 32; off; off >>= 1) s += __shfl_down(s, off, 64);
  if ((k & 63) == 0) red[k >> 6] = s;
  __syncthreads();
  if (k == 0) {
    float H = 0.0f;
    #pragma unroll
    for (int i = 0; i < 8; ++i) H += red[i];
    out[PERP_OFF] = expf(-H);
    out[0] = 1.25f * accum[0] * (1.0f / 8388608.0f);
  }
}

extern "C" void kernel_launch(void* const* d_in, const int* in_sizes, int n_in,
                              void* d_out, int out_size, void* d_ws, size_t ws_size,
                              hipStream_t stream) {
  const float* x = (const float*)d_in[0];
  const float* W = (const float*)d_in[1];
  float* out   = (float*)d_out;
  float* quant = out + QUANT_OFF;
  float* enc   = out + ENC_OFF;

  char* ws = (char*)d_ws;
  unsigned int* counts = (unsigned int*)ws;
  float* accum         = (float*)(ws + 2048);
  float* sw2           = (float*)(ws + 4096);

  hipMemsetAsync(ws, 0, 4096, stream);
  vq_prep<<<512, 64, 0, stream>>>(W, sw2);
  vq_main<<<512, 256, 0, stream>>>(x, W, sw2, enc, quant, counts, accum);
  vq_final<<<1, 512, 0, stream>>>(counts, accum, out);
}